// Round 1
// baseline (571.692 us; speedup 1.0000x reference)
//
#include <hip/hip_runtime.h>

// Problem constants
#define N_ROWS 16384   // B*T
#define C_DIM  1024
#define GV     640     // G*V
#define V_DIM  320
#define G_DIM  2
#define D_DIM  256
#define NG     32768   // N_ROWS * G

// ---------------- GEMM: logits[n, gv] = sum_c x[n,c] * W[gv,c] + b[gv] ----------------
#define BM 64
#define BN 64
#define BK 16

__global__ __launch_bounds__(256) void gemm_logits_kernel(
    const float* __restrict__ A,     // [N_ROWS, C_DIM]
    const float* __restrict__ W,     // [GV, C_DIM]
    const float* __restrict__ bias,  // [GV]
    float* __restrict__ out)         // [N_ROWS, GV]
{
  __shared__ float As[BK][BM + 1];
  __shared__ float Bs[BK][BN + 1];
  const int tid = threadIdx.x;
  const int bm0 = blockIdx.y * BM;
  const int bn0 = blockIdx.x * BN;
  const int tx = tid & 15;        // 0..15 -> 4 cols each
  const int ty = tid >> 4;        // 0..15 -> 4 rows each
  const int lr = tid >> 2;        // 0..63 load row
  const int lk = (tid & 3) << 2;  // 0,4,8,12 load k offset

  float acc[4][4] = {};
  const float* Aptr = A + (size_t)(bm0 + lr) * C_DIM + lk;
  const float* Wptr = W + (size_t)(bn0 + lr) * C_DIM + lk;

  for (int k0 = 0; k0 < C_DIM; k0 += BK) {
    float4 a4 = *(const float4*)(Aptr + k0);
    float4 b4 = *(const float4*)(Wptr + k0);
    As[lk + 0][lr] = a4.x; As[lk + 1][lr] = a4.y;
    As[lk + 2][lr] = a4.z; As[lk + 3][lr] = a4.w;
    Bs[lk + 0][lr] = b4.x; Bs[lk + 1][lr] = b4.y;
    Bs[lk + 2][lr] = b4.z; Bs[lk + 3][lr] = b4.w;
    __syncthreads();
#pragma unroll
    for (int kk = 0; kk < BK; ++kk) {
      float av[4], bv[4];
#pragma unroll
      for (int i = 0; i < 4; ++i) av[i] = As[kk][ty * 4 + i];
#pragma unroll
      for (int j = 0; j < 4; ++j) bv[j] = Bs[kk][tx * 4 + j];
#pragma unroll
      for (int i = 0; i < 4; ++i)
#pragma unroll
        for (int j = 0; j < 4; ++j)
          acc[i][j] = fmaf(av[i], bv[j], acc[i][j]);
    }
    __syncthreads();
  }

#pragma unroll
  for (int i = 0; i < 4; ++i) {
    const int m = bm0 + ty * 4 + i;
#pragma unroll
    for (int j = 0; j < 4; ++j) {
      const int v = bn0 + tx * 4 + j;
      out[(size_t)m * GV + v] = acc[i][j] + bias[v];
    }
  }
}

// ---------------- Row kernel: one wave per (n,g) row ----------------
// Per row r (n = r>>1, g = r&1):
//   l[v] = logits[n, g*320 + v]
//   k = argmax(l)                      -> counts[g*320+k] += 1
//   p = softmax(l)                     -> avg_sum[g*320+v] += p[v]
//   t[v] = (l[v] + gumbel[r,v]) * 0.5
//   idx = argmax(t); s = 1/sum(exp(t - tmax)); yv = (1+s)-s
//   q[n, g*256 + d] = yv * codebook[g*320+idx, d]
#define ROWS_PER_WAVE 8
#define WAVES_PER_BLOCK 4
#define ROWS_PER_BLOCK (ROWS_PER_WAVE * WAVES_PER_BLOCK)  // 32

__global__ __launch_bounds__(256) void row_kernel(
    const float* __restrict__ logits,   // [N_ROWS, GV]
    const float* __restrict__ gn,       // [NG, V_DIM]
    const float* __restrict__ cb,       // [GV, D_DIM]
    float* __restrict__ q,              // [N_ROWS, G*D] = [N_ROWS, 512]
    float* __restrict__ avg_sum,        // [GV] global accumulator (pre-zeroed)
    int* __restrict__ counts)           // [GV] global accumulator (pre-zeroed)
{
  __shared__ float accL[GV];
  __shared__ int cntL[GV];
  const int tid = threadIdx.x;
  for (int e = tid; e < GV; e += 256) { accL[e] = 0.0f; cntL[e] = 0; }
  __syncthreads();

  const int lane = tid & 63;
  const int w = tid >> 6;
  const int r0 = blockIdx.x * ROWS_PER_BLOCK + w * ROWS_PER_WAVE;  // multiple of 8

  float pacc[G_DIM][5] = {};

#pragma unroll
  for (int i = 0; i < ROWS_PER_WAVE; ++i) {
    const int g = i & 1;          // r0 is even, so (r0+i)&1 == i&1 (compile-time)
    const int r = r0 + i;
    const int n = r >> 1;
    const float* lp = logits + (size_t)n * GV + g * V_DIM;
    const float* gp = gn + (size_t)r * V_DIM;

    float l[5], t[5];
#pragma unroll
    for (int j = 0; j < 5; ++j) {
      const int v = lane + 64 * j;
      l[j] = lp[v];
      t[j] = (l[j] + gp[v]) * 0.5f;
    }

    // argmax of l (first index on ties)
    float m = l[0]; int mi = lane;
#pragma unroll
    for (int j = 1; j < 5; ++j) {
      const int v = lane + 64 * j;
      if (l[j] > m) { m = l[j]; mi = v; }
    }
#pragma unroll
    for (int off = 32; off > 0; off >>= 1) {
      const float om = __shfl_xor(m, off, 64);
      const int omi = __shfl_xor(mi, off, 64);
      if (om > m || (om == m && omi < mi)) { m = om; mi = omi; }
    }
    if (lane == 0) atomicAdd(&cntL[g * V_DIM + mi], 1);

    // softmax of l
    float e[5], s = 0.0f;
#pragma unroll
    for (int j = 0; j < 5; ++j) { e[j] = expf(l[j] - m); s += e[j]; }
#pragma unroll
    for (int off = 32; off > 0; off >>= 1) s += __shfl_xor(s, off, 64);
    const float inv = 1.0f / s;
#pragma unroll
    for (int j = 0; j < 5; ++j) pacc[g][j] += e[j] * inv;

    // gumbel path: argmax of t, softmax max value
    float tm = t[0]; int ti = lane;
#pragma unroll
    for (int j = 1; j < 5; ++j) {
      const int v = lane + 64 * j;
      if (t[j] > tm) { tm = t[j]; ti = v; }
    }
#pragma unroll
    for (int off = 32; off > 0; off >>= 1) {
      const float om = __shfl_xor(tm, off, 64);
      const int omi = __shfl_xor(ti, off, 64);
      if (om > tm || (om == tm && omi < ti)) { tm = om; ti = omi; }
    }
    float ts = 0.0f;
#pragma unroll
    for (int j = 0; j < 5; ++j) ts += expf(t[j] - tm);
#pragma unroll
    for (int off = 32; off > 0; off >>= 1) ts += __shfl_xor(ts, off, 64);
    const float sv = 1.0f / ts;
    const float yv = (1.0f + sv) - sv;  // mimic y_hard + y_soft - y_soft at argmax

    // q row write: 256 floats = 64 lanes x float4
    const float4* cbp = (const float4*)(cb + ((size_t)(g * V_DIM + ti)) * D_DIM);
    const float4 c4 = cbp[lane];
    float4 o4;
    o4.x = yv * c4.x; o4.y = yv * c4.y; o4.z = yv * c4.z; o4.w = yv * c4.w;
    ((float4*)q)[(size_t)n * 128 + g * 64 + lane] = o4;
  }

  // fold per-lane accumulators into LDS, then one global atomic pass per block
#pragma unroll
  for (int g2 = 0; g2 < G_DIM; ++g2)
#pragma unroll
    for (int j = 0; j < 5; ++j)
      atomicAdd(&accL[g2 * V_DIM + lane + 64 * j], pacc[g2][j]);
  __syncthreads();

  for (int e2 = tid; e2 < GV; e2 += 256) {
    const float a = accL[e2];
    if (a != 0.0f) atomicAdd(&avg_sum[e2], a);
    const int c = cntL[e2];
    if (c) atomicAdd(&counts[e2], c);
  }
}

// ---------------- Finalize: perplexities + diversity loss ----------------
__global__ void finalize_kernel(const float* __restrict__ avg_sum,
                                const int* __restrict__ counts,
                                float* __restrict__ out3)
{
  const int lane = threadIdx.x;  // 64 threads
  float sc[G_DIM] = {0.0f, 0.0f};
  float sa[G_DIM] = {0.0f, 0.0f};
#pragma unroll
  for (int g = 0; g < G_DIM; ++g) {
#pragma unroll
    for (int j = 0; j < 5; ++j) {
      const int v = lane + 64 * j;
      const float ph = (float)counts[g * V_DIM + v] * (1.0f / 16384.0f);
      sc[g] += ph * logf(ph + 1e-7f);
      const float pa = avg_sum[g * V_DIM + v] * (1.0f / 16384.0f);
      sa[g] += pa * logf(pa + 1e-7f);
    }
  }
#pragma unroll
  for (int off = 32; off > 0; off >>= 1) {
    sc[0] += __shfl_xor(sc[0], off, 64);
    sc[1] += __shfl_xor(sc[1], off, 64);
    sa[0] += __shfl_xor(sa[0], off, 64);
    sa[1] += __shfl_xor(sa[1], off, 64);
  }
  if (lane == 0) {
    const float code_p = expf(-sc[0]) + expf(-sc[1]);
    const float prob_p = expf(-sa[0]) + expf(-sa[1]);
    out3[0] = code_p;
    out3[1] = prob_p;
    out3[2] = ((float)GV - prob_p) / (float)GV;
  }
}

extern "C" void kernel_launch(void* const* d_in, const int* in_sizes, int n_in,
                              void* d_out, int out_size, void* d_ws, size_t ws_size,
                              hipStream_t stream) {
  const float* x  = (const float*)d_in[0];  // [8,2048,1024]
  const float* W  = (const float*)d_in[1];  // [640,1024]
  const float* b  = (const float*)d_in[2];  // [640]
  const float* cb = (const float*)d_in[3];  // [1,640,256]
  const float* gn = (const float*)d_in[4];  // [32768,320]
  float* out = (float*)d_out;               // q [16384*512] + 3 scalars

  float* logits = (float*)d_ws;                       // N_ROWS*GV floats
  float* avg_sum = logits + (size_t)N_ROWS * GV;      // GV floats
  int* counts = (int*)(avg_sum + GV);                 // GV ints

  hipMemsetAsync(avg_sum, 0, GV * sizeof(float) * 2, stream);

  dim3 ggrid(GV / BN, N_ROWS / BM);
  gemm_logits_kernel<<<ggrid, 256, 0, stream>>>(x, W, b, logits);

  row_kernel<<<NG / ROWS_PER_BLOCK, 256, 0, stream>>>(logits, gn, cb, out,
                                                      avg_sum, counts);

  finalize_kernel<<<1, 64, 0, stream>>>(avg_sum, counts,
                                        out + (size_t)N_ROWS * 512);
}

// Round 2
// 293.003 us; speedup vs baseline: 1.9511x; 1.9511x over previous
//
#include <hip/hip_runtime.h>

// Problem constants
#define N_ROWS 16384   // B*T
#define C_DIM  1024
#define GV     640     // G*V
#define V_DIM  320
#define G_DIM  2
#define D_DIM  256
#define NG     32768   // N_ROWS * G

typedef __attribute__((ext_vector_type(8))) _Float16 half8;
typedef __attribute__((ext_vector_type(4))) _Float16 half4;
typedef __attribute__((ext_vector_type(4))) float float4v;

#define LDS_AS(p) ((__attribute__((address_space(3))) unsigned int*)(p))
#define GLB_AS(p) ((const __attribute__((address_space(1))) unsigned int*)(p))

// ---------------- Split fp32 -> fp16 hi + fp16 lo ----------------
__global__ __launch_bounds__(256) void split_kernel(const float* __restrict__ src,
                                                    _Float16* __restrict__ hi,
                                                    _Float16* __restrict__ lo,
                                                    int n4) {
  const int i = blockIdx.x * 256 + threadIdx.x;
  if (i >= n4) return;
  const float4 v = ((const float4*)src)[i];
  half4 h, l;
  h.x = (_Float16)v.x; l.x = (_Float16)(v.x - (float)h.x);
  h.y = (_Float16)v.y; l.y = (_Float16)(v.y - (float)h.y);
  h.z = (_Float16)v.z; l.z = (_Float16)(v.z - (float)h.z);
  h.w = (_Float16)v.w; l.w = (_Float16)(v.w - (float)h.w);
  ((half4*)hi)[i] = h;
  ((half4*)lo)[i] = l;
}

// ---------------- MFMA GEMM: logits = x @ W^T + b  (split fp16, fp32 acc) ----------------
// 128x128 block tile, BK=32, 4 waves each 64x64, 16x16x32 f16 MFMA, 3 products.
__global__ __launch_bounds__(256) void gemm_mfma_kernel(
    const _Float16* __restrict__ xh, const _Float16* __restrict__ xl,
    const _Float16* __restrict__ wh, const _Float16* __restrict__ wl,
    const float* __restrict__ bias, float* __restrict__ out) {
  __shared__ _Float16 Ah[128 * 32];
  __shared__ _Float16 Al[128 * 32];
  __shared__ _Float16 Bh[128 * 32];
  __shared__ _Float16 Bl[128 * 32];

  const int tid = threadIdx.x;
  const int lane = tid & 63;
  const int w = tid >> 6;
  const int m0 = blockIdx.y * 128;
  const int n0 = blockIdx.x * 128;

  // staging: each wave stages 32 rows of each tile (two 16-row instrs per array)
  const int srow = lane >> 2;        // 0..15
  const int skoff = (lane & 3) * 8;  // 0,8,16,24 (halves)
  const _Float16* gAh = xh + (size_t)(m0 + w * 32 + srow) * C_DIM + skoff;
  const _Float16* gAl = xl + (size_t)(m0 + w * 32 + srow) * C_DIM + skoff;
  const _Float16* gBh = wh + (size_t)(n0 + w * 32 + srow) * C_DIM + skoff;
  const _Float16* gBl = wl + (size_t)(n0 + w * 32 + srow) * C_DIM + skoff;
  _Float16* lAh = Ah + (w * 32) * 32;
  _Float16* lAl = Al + (w * 32) * 32;
  _Float16* lBh = Bh + (w * 32) * 32;
  _Float16* lBl = Bl + (w * 32) * 32;
  const size_t rstep = (size_t)16 * C_DIM;

  const int wm = (w & 1) * 64;
  const int wn = (w >> 1) * 64;
  const int frow = lane & 15;
  const int fk = (lane >> 4) * 8;

  float4v acc[4][4];
#pragma unroll
  for (int i = 0; i < 4; ++i)
#pragma unroll
    for (int j = 0; j < 4; ++j) acc[i][j] = (float4v)0.0f;

  for (int k0 = 0; k0 < C_DIM; k0 += 32) {
    __builtin_amdgcn_global_load_lds(GLB_AS(gAh + k0),         LDS_AS(lAh),            16, 0, 0);
    __builtin_amdgcn_global_load_lds(GLB_AS(gAh + rstep + k0), LDS_AS(lAh + 16 * 32),  16, 0, 0);
    __builtin_amdgcn_global_load_lds(GLB_AS(gAl + k0),         LDS_AS(lAl),            16, 0, 0);
    __builtin_amdgcn_global_load_lds(GLB_AS(gAl + rstep + k0), LDS_AS(lAl + 16 * 32),  16, 0, 0);
    __builtin_amdgcn_global_load_lds(GLB_AS(gBh + k0),         LDS_AS(lBh),            16, 0, 0);
    __builtin_amdgcn_global_load_lds(GLB_AS(gBh + rstep + k0), LDS_AS(lBh + 16 * 32),  16, 0, 0);
    __builtin_amdgcn_global_load_lds(GLB_AS(gBl + k0),         LDS_AS(lBl),            16, 0, 0);
    __builtin_amdgcn_global_load_lds(GLB_AS(gBl + rstep + k0), LDS_AS(lBl + 16 * 32),  16, 0, 0);
    __syncthreads();

    half8 a_h[4], a_l[4];
#pragma unroll
    for (int i = 0; i < 4; ++i) {
      a_h[i] = *(const half8*)&Ah[(wm + i * 16 + frow) * 32 + fk];
      a_l[i] = *(const half8*)&Al[(wm + i * 16 + frow) * 32 + fk];
    }
#pragma unroll
    for (int j = 0; j < 4; ++j) {
      const half8 b_h = *(const half8*)&Bh[(wn + j * 16 + frow) * 32 + fk];
      const half8 b_l = *(const half8*)&Bl[(wn + j * 16 + frow) * 32 + fk];
#pragma unroll
      for (int i = 0; i < 4; ++i) {
        acc[i][j] = __builtin_amdgcn_mfma_f32_16x16x32_f16(a_h[i], b_h, acc[i][j], 0, 0, 0);
        acc[i][j] = __builtin_amdgcn_mfma_f32_16x16x32_f16(a_h[i], b_l, acc[i][j], 0, 0, 0);
        acc[i][j] = __builtin_amdgcn_mfma_f32_16x16x32_f16(a_l[i], b_h, acc[i][j], 0, 0, 0);
      }
    }
    __syncthreads();
  }

  // epilogue: D row=(lane>>4)*4+r, col=lane&15 per 16x16 tile
  const int quad = lane >> 4;
#pragma unroll
  for (int j = 0; j < 4; ++j) {
    const int col = n0 + wn + j * 16 + frow;
    const float bv = bias[col];
#pragma unroll
    for (int i = 0; i < 4; ++i) {
      const int rbase = m0 + wm + i * 16 + quad * 4;
#pragma unroll
      for (int r = 0; r < 4; ++r)
        out[(size_t)(rbase + r) * GV + col] = acc[i][j][r] + bv;
    }
  }
}

// ---------------- Fallback fp32 GEMM (round-1) ----------------
#define BM 64
#define BN 64
#define BK 16
__global__ __launch_bounds__(256) void gemm_logits_kernel(
    const float* __restrict__ A, const float* __restrict__ W,
    const float* __restrict__ bias, float* __restrict__ out) {
  __shared__ float As[BK][BM + 1];
  __shared__ float Bs[BK][BN + 1];
  const int tid = threadIdx.x;
  const int bm0 = blockIdx.y * BM;
  const int bn0 = blockIdx.x * BN;
  const int tx = tid & 15;
  const int ty = tid >> 4;
  const int lr = tid >> 2;
  const int lk = (tid & 3) << 2;

  float acc[4][4] = {};
  const float* Aptr = A + (size_t)(bm0 + lr) * C_DIM + lk;
  const float* Wptr = W + (size_t)(bn0 + lr) * C_DIM + lk;

  for (int k0 = 0; k0 < C_DIM; k0 += BK) {
    float4 a4 = *(const float4*)(Aptr + k0);
    float4 b4 = *(const float4*)(Wptr + k0);
    As[lk + 0][lr] = a4.x; As[lk + 1][lr] = a4.y;
    As[lk + 2][lr] = a4.z; As[lk + 3][lr] = a4.w;
    Bs[lk + 0][lr] = b4.x; Bs[lk + 1][lr] = b4.y;
    Bs[lk + 2][lr] = b4.z; Bs[lk + 3][lr] = b4.w;
    __syncthreads();
#pragma unroll
    for (int kk = 0; kk < BK; ++kk) {
      float av[4], bv[4];
#pragma unroll
      for (int i = 0; i < 4; ++i) av[i] = As[kk][ty * 4 + i];
#pragma unroll
      for (int j = 0; j < 4; ++j) bv[j] = Bs[kk][tx * 4 + j];
#pragma unroll
      for (int i = 0; i < 4; ++i)
#pragma unroll
        for (int j = 0; j < 4; ++j)
          acc[i][j] = fmaf(av[i], bv[j], acc[i][j]);
    }
    __syncthreads();
  }
#pragma unroll
  for (int i = 0; i < 4; ++i) {
    const int m = bm0 + ty * 4 + i;
#pragma unroll
    for (int j = 0; j < 4; ++j) {
      const int v = bn0 + tx * 4 + j;
      out[(size_t)m * GV + v] = acc[i][j] + bias[v];
    }
  }
}

// ---------------- Row kernel: one wave per (n,g) row ----------------
#define ROWS_PER_WAVE 8
#define WAVES_PER_BLOCK 4
#define ROWS_PER_BLOCK (ROWS_PER_WAVE * WAVES_PER_BLOCK)  // 32

__global__ __launch_bounds__(256) void row_kernel(
    const float* __restrict__ logits, const float* __restrict__ gn,
    const float* __restrict__ cb, float* __restrict__ q,
    float* __restrict__ avg_sum, int* __restrict__ counts) {
  __shared__ float accL[GV];
  __shared__ int cntL[GV];
  const int tid = threadIdx.x;
  for (int e = tid; e < GV; e += 256) { accL[e] = 0.0f; cntL[e] = 0; }
  __syncthreads();

  const int lane = tid & 63;
  const int w = tid >> 6;
  const int r0 = blockIdx.x * ROWS_PER_BLOCK + w * ROWS_PER_WAVE;

  float pacc[G_DIM][5] = {};

#pragma unroll
  for (int i = 0; i < ROWS_PER_WAVE; ++i) {
    const int g = i & 1;
    const int r = r0 + i;
    const int n = r >> 1;
    const float* lp = logits + (size_t)n * GV + g * V_DIM;
    const float* gp = gn + (size_t)r * V_DIM;

    float l[5], t[5];
#pragma unroll
    for (int j = 0; j < 5; ++j) {
      const int v = lane + 64 * j;
      l[j] = lp[v];
      t[j] = (l[j] + gp[v]) * 0.5f;
    }

    float m = l[0]; int mi = lane;
#pragma unroll
    for (int j = 1; j < 5; ++j) {
      const int v = lane + 64 * j;
      if (l[j] > m) { m = l[j]; mi = v; }
    }
#pragma unroll
    for (int off = 32; off > 0; off >>= 1) {
      const float om = __shfl_xor(m, off, 64);
      const int omi = __shfl_xor(mi, off, 64);
      if (om > m || (om == m && omi < mi)) { m = om; mi = omi; }
    }
    if (lane == 0) atomicAdd(&cntL[g * V_DIM + mi], 1);

    float e[5], s = 0.0f;
#pragma unroll
    for (int j = 0; j < 5; ++j) { e[j] = expf(l[j] - m); s += e[j]; }
#pragma unroll
    for (int off = 32; off > 0; off >>= 1) s += __shfl_xor(s, off, 64);
    const float inv = 1.0f / s;
#pragma unroll
    for (int j = 0; j < 5; ++j) pacc[g][j] += e[j] * inv;

    float tm = t[0]; int ti = lane;
#pragma unroll
    for (int j = 1; j < 5; ++j) {
      const int v = lane + 64 * j;
      if (t[j] > tm) { tm = t[j]; ti = v; }
    }
#pragma unroll
    for (int off = 32; off > 0; off >>= 1) {
      const float om = __shfl_xor(tm, off, 64);
      const int omi = __shfl_xor(ti, off, 64);
      if (om > tm || (om == tm && omi < ti)) { tm = om; ti = omi; }
    }
    float ts = 0.0f;
#pragma unroll
    for (int j = 0; j < 5; ++j) ts += expf(t[j] - tm);
#pragma unroll
    for (int off = 32; off > 0; off >>= 1) ts += __shfl_xor(ts, off, 64);
    const float sv = 1.0f / ts;
    const float yv = (1.0f + sv) - sv;

    const float4* cbp = (const float4*)(cb + ((size_t)(g * V_DIM + ti)) * D_DIM);
    const float4 c4 = cbp[lane];
    float4 o4;
    o4.x = yv * c4.x; o4.y = yv * c4.y; o4.z = yv * c4.z; o4.w = yv * c4.w;
    ((float4*)q)[(size_t)n * 128 + g * 64 + lane] = o4;
  }

#pragma unroll
  for (int g2 = 0; g2 < G_DIM; ++g2)
#pragma unroll
    for (int j = 0; j < 5; ++j)
      atomicAdd(&accL[g2 * V_DIM + lane + 64 * j], pacc[g2][j]);
  __syncthreads();

  for (int e2 = tid; e2 < GV; e2 += 256) {
    const float a = accL[e2];
    if (a != 0.0f) atomicAdd(&avg_sum[e2], a);
    const int c = cntL[e2];
    if (c) atomicAdd(&counts[e2], c);
  }
}

// ---------------- Finalize ----------------
__global__ void finalize_kernel(const float* __restrict__ avg_sum,
                                const int* __restrict__ counts,
                                float* __restrict__ out3) {
  const int lane = threadIdx.x;
  float sc[G_DIM] = {0.0f, 0.0f};
  float sa[G_DIM] = {0.0f, 0.0f};
#pragma unroll
  for (int g = 0; g < G_DIM; ++g) {
#pragma unroll
    for (int j = 0; j < 5; ++j) {
      const int v = lane + 64 * j;
      const float ph = (float)counts[g * V_DIM + v] * (1.0f / 16384.0f);
      sc[g] += ph * logf(ph + 1e-7f);
      const float pa = avg_sum[g * V_DIM + v] * (1.0f / 16384.0f);
      sa[g] += pa * logf(pa + 1e-7f);
    }
  }
#pragma unroll
  for (int off = 32; off > 0; off >>= 1) {
    sc[0] += __shfl_xor(sc[0], off, 64);
    sc[1] += __shfl_xor(sc[1], off, 64);
    sa[0] += __shfl_xor(sa[0], off, 64);
    sa[1] += __shfl_xor(sa[1], off, 64);
  }
  if (lane == 0) {
    const float code_p = expf(-sc[0]) + expf(-sc[1]);
    const float prob_p = expf(-sa[0]) + expf(-sa[1]);
    out3[0] = code_p;
    out3[1] = prob_p;
    out3[2] = ((float)GV - prob_p) / (float)GV;
  }
}

extern "C" void kernel_launch(void* const* d_in, const int* in_sizes, int n_in,
                              void* d_out, int out_size, void* d_ws, size_t ws_size,
                              hipStream_t stream) {
  const float* x  = (const float*)d_in[0];
  const float* W  = (const float*)d_in[1];
  const float* b  = (const float*)d_in[2];
  const float* cb = (const float*)d_in[3];
  const float* gn = (const float*)d_in[4];
  float* out = (float*)d_out;

  char* ws = (char*)d_ws;
  float* logits  = (float*)ws;                                  // 41,943,040 B
  float* avg_sum = (float*)(ws + 41943040);                     // 2,560 B
  int*   counts  = (int*)  (ws + 41945600);                     // 2,560 B
  _Float16* xh = (_Float16*)(ws + 41948160);                    // 33,554,432 B
  _Float16* xl = (_Float16*)(ws + 75502592);                    // 33,554,432 B
  _Float16* wh = (_Float16*)(ws + 109057024);                   // 1,310,720 B
  _Float16* wl = (_Float16*)(ws + 110367744);                   // 1,310,720 B
  const size_t ws_needed = 111678464;

  hipMemsetAsync(avg_sum, 0, GV * sizeof(float) * 2, stream);

  if (ws_size >= ws_needed) {
    split_kernel<<<(N_ROWS * C_DIM / 4 + 255) / 256, 256, 0, stream>>>(x, xh, xl, N_ROWS * C_DIM / 4);
    split_kernel<<<(GV * C_DIM / 4 + 255) / 256, 256, 0, stream>>>(W, wh, wl, GV * C_DIM / 4);
    dim3 ggrid(GV / 128, N_ROWS / 128);  // (5, 128)
    gemm_mfma_kernel<<<ggrid, 256, 0, stream>>>(xh, xl, wh, wl, b, logits);
  } else {
    dim3 ggrid(GV / BN, N_ROWS / BM);
    gemm_logits_kernel<<<ggrid, 256, 0, stream>>>(x, W, b, logits);
  }

  row_kernel<<<NG / ROWS_PER_BLOCK, 256, 0, stream>>>(logits, gn, cb, out,
                                                      avg_sum, counts);
  finalize_kernel<<<1, 64, 0, stream>>>(avg_sum, counts,
                                        out + (size_t)N_ROWS * 512);
}